// Round 6
// baseline (580.337 us; speedup 1.0000x reference)
//
#include <hip/hip_runtime.h>
#include <hip/hip_bf16.h>

#define Hd 128
#define Nn 50000
#define Ee 400000
#define Bb 2
#define NROWS 100000          // B*N flat node rows
#define NT 12500              // Bb * Ee/64 edge tiles
#define CHUNK 6               // tiles per block (pipelined)

typedef __attribute__((ext_vector_type(8))) short bf16x8;
typedef __attribute__((ext_vector_type(4))) short bf16x4;
typedef __attribute__((ext_vector_type(4))) float f32x4;

static __device__ __forceinline__ short f2bf(float f) {
    __hip_bfloat16 h = __float2bfloat16(f);
    return *reinterpret_cast<short*>(&h);
}
static __device__ __forceinline__ float bf2f(short s) {
    union { unsigned u; float f; } v; v.u = ((unsigned)(unsigned short)s) << 16;
    return v.f;
}
static __device__ __forceinline__ bf16x8 cvt8(float4 a, float4 b) {
    bf16x8 r;
    r[0] = f2bf(a.x); r[1] = f2bf(a.y); r[2] = f2bf(a.z); r[3] = f2bf(a.w);
    r[4] = f2bf(b.x); r[5] = f2bf(b.y); r[6] = f2bf(b.z); r[7] = f2bf(b.w);
    return r;
}
static __device__ __forceinline__ unsigned pk2(float a, float b) {
    return (unsigned)(unsigned short)f2bf(a) | ((unsigned)(unsigned short)f2bf(b) << 16);
}
// LDS-only barrier: does NOT drain vmcnt -> global loads/stores stay in flight.
static __device__ __forceinline__ void lds_barrier() {
    asm volatile("s_waitcnt lgkmcnt(0)" ::: "memory");
    __builtin_amdgcn_s_barrier();
    asm volatile("" ::: "memory");
}

// wbuf layout (shorts): WabT[256][128] @0 | W1cT[128][128] @32768 | W2T[128][128] @49152
//                       Wn1T[128][256] @65536 | Wn2T[128][128] @98304   (total 114688)
__global__ void prep_weights(const float* __restrict__ We1, const float* __restrict__ We2,
                             const float* __restrict__ Wn1, const float* __restrict__ Wn2,
                             short* __restrict__ wbuf) {
    int gid = blockIdx.x * 256 + threadIdx.x;
    if (gid < 32768) {
        int c = gid >> 7, k = gid & 127;
        float v = (c < 128) ? We1[k * 128 + c] : We1[(k + 128) * 128 + (c - 128)];
        wbuf[gid] = f2bf(v); return;
    }
    int g = gid - 32768;
    if (g < 16384) { int c = g >> 7, k = g & 127; wbuf[gid] = f2bf(We1[(k + 256) * 128 + c]); return; }
    g -= 16384;
    if (g < 16384) { int c = g >> 7, k = g & 127; wbuf[gid] = f2bf(We2[k * 128 + c]); return; }
    g -= 16384;
    if (g < 32768) { int c = g >> 8, k = g & 255; wbuf[gid] = f2bf(Wn1[k * 128 + c]); return; }
    g -= 32768;
    if (g < 16384) { int c = g >> 7, k = g & 127; wbuf[gid] = f2bf(Wn2[k * 128 + c]); }
}

// ---- CSR by dest ----
__global__ void hist_kernel(const int* __restrict__ ei, int* __restrict__ cnt) {
    int t = blockIdx.x * 256 + threadIdx.x;
    if (t < Ee) atomicAdd(&cnt[ei[Ee + t]], 1);
}
__global__ void scan1(const int* __restrict__ cnt, int* __restrict__ cur, int* __restrict__ part) {
    __shared__ int s[256];
    int i = blockIdx.x * 256 + threadIdx.x;
    int v = (i < Nn) ? cnt[i] : 0;
    s[threadIdx.x] = v; __syncthreads();
    #pragma unroll
    for (int off = 1; off < 256; off <<= 1) {
        int u = (threadIdx.x >= off) ? s[threadIdx.x - off] : 0;
        __syncthreads(); s[threadIdx.x] += u; __syncthreads();
    }
    if (i < Nn) cur[i] = s[threadIdx.x] - v;
    if (threadIdx.x == 255) part[blockIdx.x] = s[255];
}
__global__ void scan2(int* __restrict__ part) {
    if (threadIdx.x == 0 && blockIdx.x == 0) {
        int run = 0;
        for (int i = 0; i < 196; i++) { int t = part[i]; part[i] = run; run += t; }
    }
}
__global__ void scan3(int* __restrict__ cur, const int* __restrict__ part, int* __restrict__ rp) {
    int i = blockIdx.x * 256 + threadIdx.x;
    if (i < Nn) { int v = cur[i] + part[blockIdx.x]; cur[i] = v; rp[i] = v; }
    if (i == 0 && blockIdx.x == 0) rp[Nn] = Ee;
}
__global__ void scatter_k(const int* __restrict__ ei, int* __restrict__ cur, int* __restrict__ elist) {
    int t = blockIdx.x * 256 + threadIdx.x;
    if (t < Ee) { int d = ei[Ee + t]; int pos = atomicAdd(&cur[d], 1); elist[pos] = t; }
}

// ---- node_pre: xa = x@W1a, xb = x@W1b (bf16 out, no bias) ----
__global__ __launch_bounds__(256) void node_pre(
    const float* __restrict__ x, const short* __restrict__ WabT,
    short* __restrict__ xa, short* __restrict__ xb)
{
    __shared__ __align__(16) short X[32 * 128];

    const int nbase = blockIdx.x * 32;
    const int t = threadIdx.x;
    const int wv = t >> 6, lane = t & 63;
    const int row16 = lane & 15, kg = lane >> 4;

    {
        int g = t >> 3, q = t & 7;
        const float* src = x + ((size_t)(nbase + g)) * Hd + q * 16;
        float4 a0 = ((const float4*)src)[0], a1 = ((const float4*)src)[1];
        float4 a2 = ((const float4*)src)[2], a3 = ((const float4*)src)[3];
        ((bf16x8*)X)[g * 16 + ((q * 2) ^ (g & 7))]     = cvt8(a0, a1);
        ((bf16x8*)X)[g * 16 + ((q * 2 + 1) ^ (g & 7))] = cvt8(a2, a3);
    }

    bf16x8 wf[4][4];
    #pragma unroll
    for (int nt = 0; nt < 4; nt++) {
        int n = wv * 64 + nt * 16 + row16;
        #pragma unroll
        for (int kt = 0; kt < 4; kt++)
            wf[kt][nt] = *(const bf16x8*)(WabT + n * 128 + kt * 32 + kg * 8);
    }
    __syncthreads();

    f32x4 acc[2][4];
    #pragma unroll
    for (int mt = 0; mt < 2; mt++)
        #pragma unroll
        for (int nt = 0; nt < 4; nt++) acc[mt][nt] = (f32x4){0.f,0.f,0.f,0.f};

    #pragma unroll
    for (int mt = 0; mt < 2; mt++) {
        int row = mt * 16 + row16;
        #pragma unroll
        for (int kt = 0; kt < 4; kt++) {
            bf16x8 xf = ((const bf16x8*)X)[row * 16 + ((kt * 4 + kg) ^ (row & 7))];
            #pragma unroll
            for (int nt = 0; nt < 4; nt++)
                acc[mt][nt] = __builtin_amdgcn_mfma_f32_16x16x32_bf16(wf[kt][nt], xf, acc[mt][nt], 0, 0, 0);
        }
    }

    #pragma unroll
    for (int mt = 0; mt < 2; mt++) {
        size_t node = nbase + mt * 16 + row16;
        #pragma unroll
        for (int nt = 0; nt < 4; nt++) {
            int ch = wv * 64 + nt * 16 + kg * 4;
            uint2 pk = { pk2(acc[mt][nt][0], acc[mt][nt][1]), pk2(acc[mt][nt][2], acc[mt][nt][3]) };
            short* dst = (ch < 128) ? (xa + node * Hd + ch) : (xb + node * Hd + (ch - 128));
            *(uint2*)dst = pk;
        }
    }
}

// ---- edge_mlp: e = relu(ea@W1c + xa[src] + xb[dest] + be1) @ W2 + be2 ----
// Cross-tile software pipeline: 6 tiles/block, reg-staged ea for t+1 during compute of t,
// raw LDS-only barriers (no vmcnt drain), weights pinned in VGPRs, direct e stores.
__global__ __launch_bounds__(512, 4) void edge_mlp(
    const float* __restrict__ ea, const int* __restrict__ ei,
    const short* __restrict__ xa, const short* __restrict__ xb,
    const short* __restrict__ W1cT, const float* __restrict__ be1,
    const short* __restrict__ W2T, const float* __restrict__ be2,
    float* __restrict__ e_out)
{
    __shared__ __align__(16) short Aea[2][64 * 128];   // 2x16KB double-buffered input tile
    __shared__ __align__(16) short A2[64 * 128];       // 16KB hidden tile

    const int t = threadIdx.x;
    const int wv = t >> 6, lane = t & 63;
    const int row16 = lane & 15, kg = lane >> 4;
    const int n0 = wv * 16 + kg * 4;        // this lane's 4 output channels
    const int srow = t >> 3, sq = t & 7;    // staging: row, 64B-quarter

    // weights for this wave's 16 cols, pinned in VGPRs
    bf16x8 w1[4], w2[4];
    {
        const short* wp1 = W1cT + (wv * 16 + row16) * 128 + kg * 8;
        const short* wp2 = W2T  + (wv * 16 + row16) * 128 + kg * 8;
        #pragma unroll
        for (int kt = 0; kt < 4; kt++) {
            w1[kt] = *(const bf16x8*)(wp1 + kt * 32);
            w2[kt] = *(const bf16x8*)(wp2 + kt * 32);
        }
    }
    #pragma unroll
    for (int kt = 0; kt < 4; kt++) { asm volatile("" : "+v"(w1[kt]), "+v"(w2[kt])); }
    const float4 b1v = *(const float4*)(be1 + n0);
    const float4 b2v = *(const float4*)(be2 + n0);

    int tile = blockIdx.x * CHUNK;

    // ---- prologue: stage tile0 into registers ----
    float4 er0, er1, er2, er3;
    bf16x4 av[4], bv[4];
    if (tile < NT) {
        int b = tile / (Ee / 64);
        int ebase = (tile % (Ee / 64)) * 64;
        const float* src = ea + ((size_t)b * Ee + ebase + srow) * Hd + sq * 16;
        er0 = ((const float4*)src)[0]; er1 = ((const float4*)src)[1];
        er2 = ((const float4*)src)[2]; er3 = ((const float4*)src)[3];
        int sn[4], dn[4];
        #pragma unroll
        for (int mt = 0; mt < 4; mt++) {
            int eidx = ebase + mt * 16 + row16;
            sn[mt] = ei[eidx]; dn[mt] = ei[Ee + eidx];
        }
        const short* xab = xa + (size_t)b * Nn * Hd;
        const short* xbb = xb + (size_t)b * Nn * Hd;
        #pragma unroll
        for (int mt = 0; mt < 4; mt++) {
            av[mt] = *(const bf16x4*)(xab + (size_t)sn[mt] * Hd + n0);
            bv[mt] = *(const bf16x4*)(xbb + (size_t)dn[mt] * Hd + n0);
        }
    }

    int cur = 0;
    for (int it = 0; it < CHUNK; ++it) {
        const bool v = (tile < NT);
        const int b = tile / (Ee / 64);
        const size_t ebase = (size_t)(tile % (Ee / 64)) * 64;

        // phase 1: staged regs -> LDS[cur]
        if (v) {
            ((bf16x8*)Aea[cur])[srow * 16 + ((sq * 2)     ^ (srow & 7))] = cvt8(er0, er1);
            ((bf16x8*)Aea[cur])[srow * 16 + ((sq * 2 + 1) ^ (srow & 7))] = cvt8(er2, er3);
        }
        lds_barrier();

        // phase 2: issue next tile's ea + ei loads (stay in flight across everything below)
        const int ntile = tile + 1;
        const bool nv = (it + 1 < CHUNK) && (ntile < NT);
        float4 ner0, ner1, ner2, ner3;
        int nsn[4], ndn[4];
        int nb = 0; int nebase = 0;
        if (nv) {
            nb = ntile / (Ee / 64);
            nebase = (ntile % (Ee / 64)) * 64;
            const float* src = ea + ((size_t)nb * Ee + nebase + srow) * Hd + sq * 16;
            ner0 = ((const float4*)src)[0]; ner1 = ((const float4*)src)[1];
            ner2 = ((const float4*)src)[2]; ner3 = ((const float4*)src)[3];
            #pragma unroll
            for (int mt = 0; mt < 4; mt++) {
                int eidx = nebase + mt * 16 + row16;
                nsn[mt] = ei[eidx]; ndn[mt] = ei[Ee + eidx];
            }
        }

        // phase 3: L1 GEMM from LDS[cur]
        f32x4 acc[4];
        #pragma unroll
        for (int mt = 0; mt < 4; mt++) acc[mt] = (f32x4){0.f,0.f,0.f,0.f};
        if (v) {
            #pragma unroll
            for (int kt = 0; kt < 4; kt++) {
                #pragma unroll
                for (int mt = 0; mt < 4; mt++) {
                    int row = mt * 16 + row16;
                    bf16x8 af = ((const bf16x8*)Aea[cur])[row * 16 + ((kt * 4 + kg) ^ (row & 7))];
                    acc[mt] = __builtin_amdgcn_mfma_f32_16x16x32_bf16(w1[kt], af, acc[mt], 0, 0, 0);
                }
            }
        }

        // phase 4: issue next tile's xa/xb gathers (one GEMM-phase + of latency cover)
        bf16x4 nav[4], nbv[4];
        if (nv) {
            const short* xab = xa + (size_t)nb * Nn * Hd;
            const short* xbb = xb + (size_t)nb * Nn * Hd;
            #pragma unroll
            for (int mt = 0; mt < 4; mt++) {
                nav[mt] = *(const bf16x4*)(xab + (size_t)nsn[mt] * Hd + n0);
                nbv[mt] = *(const bf16x4*)(xbb + (size_t)ndn[mt] * Hd + n0);
            }
        }

        // phase 5: epilogue (bias + skip adds + relu) -> A2
        if (v) {
            #pragma unroll
            for (int mt = 0; mt < 4; mt++) {
                int row = mt * 16 + row16;
                float vv[4];
                #pragma unroll
                for (int r = 0; r < 4; r++) {
                    float u = acc[mt][r] + b1v[r] + bf2f(av[mt][r]) + bf2f(bv[mt][r]);
                    vv[r] = u > 0.f ? u : 0.f;
                }
                int G = (n0 >> 3) ^ (row & 7);
                *(uint2*)((char*)A2 + row * 256 + G * 16 + (n0 & 7) * 2) =
                    (uint2){ pk2(vv[0], vv[1]), pk2(vv[2], vv[3]) };
            }
        }
        lds_barrier();

        // phase 6: L2 GEMM from A2, direct e stores (fire-and-forget)
        if (v) {
            f32x4 acc2[4];
            #pragma unroll
            for (int mt = 0; mt < 4; mt++) acc2[mt] = (f32x4){0.f,0.f,0.f,0.f};
            #pragma unroll
            for (int kt = 0; kt < 4; kt++) {
                #pragma unroll
                for (int mt = 0; mt < 4; mt++) {
                    int row = mt * 16 + row16;
                    bf16x8 hf = *(const bf16x8*)((const char*)A2 + row * 256 + (((kt * 4 + kg) ^ (row & 7)) * 16));
                    acc2[mt] = __builtin_amdgcn_mfma_f32_16x16x32_bf16(w2[kt], hf, acc2[mt], 0, 0, 0);
                }
            }
            float* eo = e_out + ((size_t)b * Ee + ebase) * Hd;
            #pragma unroll
            for (int mt = 0; mt < 4; mt++) {
                float4 ov;
                ov.x = acc2[mt][0] + b2v.x;
                ov.y = acc2[mt][1] + b2v.y;
                ov.z = acc2[mt][2] + b2v.z;
                ov.w = acc2[mt][3] + b2v.w;
                *(float4*)(eo + (size_t)(mt * 16 + row16) * Hd + n0) = ov;
            }
        }

        // rotate pipeline registers
        er0 = ner0; er1 = ner1; er2 = ner2; er3 = ner3;
        #pragma unroll
        for (int mt = 0; mt < 4; mt++) { av[mt] = nav[mt]; bv[mt] = nbv[mt]; }
        cur ^= 1; tile = ntile;
    }
}

// ---- node_mlp: CSR-gather agg from e, x_out = relu(concat(x,agg)@Wn1+bn1)@Wn2+bn2 ----
__global__ __launch_bounds__(512, 4) void node_mlp(
    const float* __restrict__ x, const float* __restrict__ e_out,
    const int* __restrict__ rp, const int* __restrict__ elist,
    const short* __restrict__ Wn1T, const float* __restrict__ bn1,
    const short* __restrict__ Wn2T, const float* __restrict__ bn2,
    float* __restrict__ xout)
{
    __shared__ __align__(16) short A[32 * 256];      // 16KB: [node][32 groups] (x | agg)
    __shared__ __align__(16) short A2[32 * 128];     // 8KB hidden

    const int tilesPerB = (Nn + 31) / 32;            // 1563
    const int bid = blockIdx.x;
    const int b = bid / tilesPerB;
    const int nbase = (bid % tilesPerB) * 32;
    const int t = threadIdx.x;
    const int wv = t >> 6, lane = t & 63;
    const int row16 = lane & 15, kg = lane >> 4;
    const int n0 = wv * 16 + kg * 4;

    // gather + stage: 16 threads per node, 8 floats (32B) each
    {
        int g = t >> 4, q2 = t & 15;
        int n = nbase + g;
        float4 xv0 = {0,0,0,0}, xv1 = xv0;
        float4 s0 = {0,0,0,0}, s1 = s0;
        if (n < Nn) {
            const float* xr = x + ((size_t)b * Nn + n) * Hd + q2 * 8;
            xv0 = ((const float4*)xr)[0]; xv1 = ((const float4*)xr)[1];
            int jb = rp[n], je = rp[n + 1];
            const float* eb = e_out + (size_t)b * Ee * Hd + q2 * 8;
            int j = jb;
            for (; j + 4 <= je; j += 4) {
                int e0 = elist[j], e1 = elist[j+1], e2 = elist[j+2], e3 = elist[j+3];
                const float* p0 = eb + (size_t)e0 * Hd;
                const float* p1 = eb + (size_t)e1 * Hd;
                const float* p2 = eb + (size_t)e2 * Hd;
                const float* p3 = eb + (size_t)e3 * Hd;
                float4 u0 = ((const float4*)p0)[0], u1 = ((const float4*)p0)[1];
                float4 u2 = ((const float4*)p1)[0], u3 = ((const float4*)p1)[1];
                float4 u4 = ((const float4*)p2)[0], u5 = ((const float4*)p2)[1];
                float4 u6 = ((const float4*)p3)[0], u7 = ((const float4*)p3)[1];
                s0.x += (u0.x + u2.x) + (u4.x + u6.x);
                s0.y += (u0.y + u2.y) + (u4.y + u6.y);
                s0.z += (u0.z + u2.z) + (u4.z + u6.z);
                s0.w += (u0.w + u2.w) + (u4.w + u6.w);
                s1.x += (u1.x + u3.x) + (u5.x + u7.x);
                s1.y += (u1.y + u3.y) + (u5.y + u7.y);
                s1.z += (u1.z + u3.z) + (u5.z + u7.z);
                s1.w += (u1.w + u3.w) + (u5.w + u7.w);
            }
            for (; j < je; j++) {
                const float* p0 = eb + (size_t)elist[j] * Hd;
                float4 u0 = ((const float4*)p0)[0], u1 = ((const float4*)p0)[1];
                s0.x += u0.x; s0.y += u0.y; s0.z += u0.z; s0.w += u0.w;
                s1.x += u1.x; s1.y += u1.y; s1.z += u1.z; s1.w += u1.w;
            }
        }
        ((bf16x8*)A)[g * 32 + (q2 ^ (g & 7))]        = cvt8(xv0, xv1);
        ((bf16x8*)A)[g * 32 + ((16 + q2) ^ (g & 7))] = cvt8(s0, s1);
    }

    bf16x8 w1[8];
    {
        const short* wp = Wn1T + (wv * 16 + row16) * 256 + kg * 8;
        #pragma unroll
        for (int kt = 0; kt < 8; kt++) w1[kt] = *(const bf16x8*)(wp + kt * 32);
    }
    __syncthreads();

    // L1 GEMM K=256
    f32x4 acc[2];
    acc[0] = (f32x4){0.f,0.f,0.f,0.f}; acc[1] = (f32x4){0.f,0.f,0.f,0.f};
    #pragma unroll
    for (int kt = 0; kt < 8; kt++) {
        #pragma unroll
        for (int mt = 0; mt < 2; mt++) {
            int row = mt * 16 + row16;
            bf16x8 af = ((const bf16x8*)A)[row * 32 + ((kt * 4 + kg) ^ (row & 7))];
            acc[mt] = __builtin_amdgcn_mfma_f32_16x16x32_bf16(w1[kt], af, acc[mt], 0, 0, 0);
        }
    }

    float4 b1v = *(const float4*)(bn1 + n0);
    bf16x8 w2[4];
    {
        const short* wp = Wn2T + (wv * 16 + row16) * 128 + kg * 8;
        #pragma unroll
        for (int kt = 0; kt < 4; kt++) w2[kt] = *(const bf16x8*)(wp + kt * 32);
    }

    #pragma unroll
    for (int mt = 0; mt < 2; mt++) {
        int row = mt * 16 + row16;
        float v[4];
        #pragma unroll
        for (int r = 0; r < 4; r++) {
            float u = acc[mt][r] + b1v[r];
            v[r] = u > 0.f ? u : 0.f;
        }
        int G = (n0 >> 3) ^ (row & 7);
        *(uint2*)((char*)A2 + row * 256 + G * 16 + (n0 & 7) * 2) = (uint2){ pk2(v[0], v[1]), pk2(v[2], v[3]) };
    }
    __syncthreads();

    // L2 GEMM K=128, direct stores
    f32x4 acc2[2];
    acc2[0] = (f32x4){0.f,0.f,0.f,0.f}; acc2[1] = (f32x4){0.f,0.f,0.f,0.f};
    #pragma unroll
    for (int kt = 0; kt < 4; kt++) {
        #pragma unroll
        for (int mt = 0; mt < 2; mt++) {
            int row = mt * 16 + row16;
            bf16x8 hf = *(const bf16x8*)((const char*)A2 + row * 256 + (((kt * 4 + kg) ^ (row & 7)) * 16));
            acc2[mt] = __builtin_amdgcn_mfma_f32_16x16x32_bf16(w2[kt], hf, acc2[mt], 0, 0, 0);
        }
    }
    float4 b2v = *(const float4*)(bn2 + n0);
    #pragma unroll
    for (int mt = 0; mt < 2; mt++) {
        int node = nbase + mt * 16 + row16;
        if (node < Nn) {
            float4 ov;
            ov.x = acc2[mt][0] + b2v.x;
            ov.y = acc2[mt][1] + b2v.y;
            ov.z = acc2[mt][2] + b2v.z;
            ov.w = acc2[mt][3] + b2v.w;
            *(float4*)(xout + ((size_t)b * Nn + node) * Hd + n0) = ov;
        }
    }
}

extern "C" void kernel_launch(void* const* d_in, const int* in_sizes, int n_in,
                              void* d_out, int out_size, void* d_ws, size_t ws_size,
                              hipStream_t stream) {
    const float* x   = (const float*)d_in[0];
    const int*   ei  = (const int*)d_in[1];
    const float* ea  = (const float*)d_in[2];
    const float* We1 = (const float*)d_in[3];
    const float* be1 = (const float*)d_in[4];
    const float* We2 = (const float*)d_in[5];
    const float* be2 = (const float*)d_in[6];
    const float* Wn1 = (const float*)d_in[7];
    const float* bn1 = (const float*)d_in[8];
    const float* Wn2 = (const float*)d_in[9];
    const float* bn2 = (const float*)d_in[10];

    float* xout  = (float*)d_out;
    float* e_out = xout + (size_t)Bb * Nn * Hd;     // outputs: x_out, then e

    short* wbuf  = (short*)d_ws;                    // 114688 shorts
    short* xa    = wbuf + 114688;                   // NROWS*128 bf16
    short* xb    = xa + (size_t)NROWS * Hd;
    int*   cnt   = (int*)(xb + (size_t)NROWS * Hd);
    int*   cur   = cnt + Nn;
    int*   rp    = cur + Nn;                        // Nn+1
    int*   part  = rp + Nn + 1;                     // 256
    int*   elist = part + 256;                      // Ee

    hipMemsetAsync(cnt, 0, Nn * sizeof(int), stream);
    prep_weights<<<448, 256, 0, stream>>>(We1, We2, Wn1, Wn2, wbuf);
    hist_kernel<<<(Ee + 255) / 256, 256, 0, stream>>>(ei, cnt);
    scan1<<<196, 256, 0, stream>>>(cnt, cur, part);
    scan2<<<1, 64, 0, stream>>>(part);
    scan3<<<196, 256, 0, stream>>>(cur, part, rp);
    scatter_k<<<(Ee + 255) / 256, 256, 0, stream>>>(ei, cur, elist);

    node_pre<<<NROWS / 32, 256, 0, stream>>>(x, wbuf, xa, xb);

    edge_mlp<<<(NT + CHUNK - 1) / CHUNK, 512, 0, stream>>>(
        ea, ei, xa, xb, wbuf + 32768, be1, wbuf + 49152, be2, e_out);

    node_mlp<<<Bb * ((Nn + 31) / 32), 512, 0, stream>>>(
        x, e_out, rp, elist, wbuf + 65536, bn1, wbuf + 98304, bn2, xout);
}

// Round 7
// 520.487 us; speedup vs baseline: 1.1150x; 1.1150x over previous
//
#include <hip/hip_runtime.h>
#include <hip/hip_bf16.h>

#define Hd 128
#define Nn 50000
#define Ee 400000
#define Bb 2
#define NROWS 100000          // B*N flat node rows
#define TPB 6250              // tiles per batch (Ee/64)
#define NT 12500              // Bb * TPB total edge tiles
#define CHUNK 8               // tiles per block (2-deep pipelined)

typedef __attribute__((ext_vector_type(8))) short bf16x8;
typedef __attribute__((ext_vector_type(4))) short bf16x4;
typedef __attribute__((ext_vector_type(4))) float f32x4;

static __device__ __forceinline__ short f2bf(float f) {
    __hip_bfloat16 h = __float2bfloat16(f);
    return *reinterpret_cast<short*>(&h);
}
static __device__ __forceinline__ float bf2f(short s) {
    union { unsigned u; float f; } v; v.u = ((unsigned)(unsigned short)s) << 16;
    return v.f;
}
static __device__ __forceinline__ bf16x8 cvt8(float4 a, float4 b) {
    bf16x8 r;
    r[0] = f2bf(a.x); r[1] = f2bf(a.y); r[2] = f2bf(a.z); r[3] = f2bf(a.w);
    r[4] = f2bf(b.x); r[5] = f2bf(b.y); r[6] = f2bf(b.z); r[7] = f2bf(b.w);
    return r;
}
static __device__ __forceinline__ unsigned pk2(float a, float b) {
    return (unsigned)(unsigned short)f2bf(a) | ((unsigned)(unsigned short)f2bf(b) << 16);
}
// LDS-only barrier: ensures this wave's LDS writes landed, then syncs.
// Does NOT drain vmcnt -> global loads/stores stay in flight across it.
static __device__ __forceinline__ void lds_barrier() {
    asm volatile("s_waitcnt lgkmcnt(0)" ::: "memory");
    __builtin_amdgcn_s_barrier();
}

// wbuf layout (shorts): WabT[256][128] @0 | W1cT[128][128] @32768 | W2T[128][128] @49152
//                       Wn1T[128][256] @65536 | Wn2T[128][128] @98304   (total 114688)
__global__ void prep_weights(const float* __restrict__ We1, const float* __restrict__ We2,
                             const float* __restrict__ Wn1, const float* __restrict__ Wn2,
                             short* __restrict__ wbuf) {
    int gid = blockIdx.x * 256 + threadIdx.x;
    if (gid < 32768) {
        int c = gid >> 7, k = gid & 127;
        float v = (c < 128) ? We1[k * 128 + c] : We1[(k + 128) * 128 + (c - 128)];
        wbuf[gid] = f2bf(v); return;
    }
    int g = gid - 32768;
    if (g < 16384) { int c = g >> 7, k = g & 127; wbuf[gid] = f2bf(We1[(k + 256) * 128 + c]); return; }
    g -= 16384;
    if (g < 16384) { int c = g >> 7, k = g & 127; wbuf[gid] = f2bf(We2[k * 128 + c]); return; }
    g -= 16384;
    if (g < 32768) { int c = g >> 8, k = g & 255; wbuf[gid] = f2bf(Wn1[k * 128 + c]); return; }
    g -= 32768;
    if (g < 16384) { int c = g >> 7, k = g & 127; wbuf[gid] = f2bf(Wn2[k * 128 + c]); }
}

// ---- CSR by dest ----
__global__ void hist_kernel(const int* __restrict__ ei, int* __restrict__ cnt) {
    int t = blockIdx.x * 256 + threadIdx.x;
    if (t < Ee) atomicAdd(&cnt[ei[Ee + t]], 1);
}
__global__ void scan1(const int* __restrict__ cnt, int* __restrict__ cur, int* __restrict__ part) {
    __shared__ int s[256];
    int i = blockIdx.x * 256 + threadIdx.x;
    int v = (i < Nn) ? cnt[i] : 0;
    s[threadIdx.x] = v; __syncthreads();
    #pragma unroll
    for (int off = 1; off < 256; off <<= 1) {
        int u = (threadIdx.x >= off) ? s[threadIdx.x - off] : 0;
        __syncthreads(); s[threadIdx.x] += u; __syncthreads();
    }
    if (i < Nn) cur[i] = s[threadIdx.x] - v;
    if (threadIdx.x == 255) part[blockIdx.x] = s[255];
}
__global__ void scan2(int* __restrict__ part) {
    if (threadIdx.x == 0 && blockIdx.x == 0) {
        int run = 0;
        for (int i = 0; i < 196; i++) { int t = part[i]; part[i] = run; run += t; }
    }
}
__global__ void scan3(int* __restrict__ cur, const int* __restrict__ part, int* __restrict__ rp) {
    int i = blockIdx.x * 256 + threadIdx.x;
    if (i < Nn) { int v = cur[i] + part[blockIdx.x]; cur[i] = v; rp[i] = v; }
    if (i == 0 && blockIdx.x == 0) rp[Nn] = Ee;
}
__global__ void scatter_k(const int* __restrict__ ei, int* __restrict__ cur, int* __restrict__ elist) {
    int t = blockIdx.x * 256 + threadIdx.x;
    if (t < Ee) { int d = ei[Ee + t]; int pos = atomicAdd(&cur[d], 1); elist[pos] = t; }
}

// ---- node_pre: xa = x@W1a, xb = x@W1b (bf16 out, no bias) ----
__global__ __launch_bounds__(256) void node_pre(
    const float* __restrict__ x, const short* __restrict__ WabT,
    short* __restrict__ xa, short* __restrict__ xb)
{
    __shared__ __align__(16) short X[32 * 128];

    const int nbase = blockIdx.x * 32;
    const int t = threadIdx.x;
    const int wv = t >> 6, lane = t & 63;
    const int row16 = lane & 15, kg = lane >> 4;

    {
        int g = t >> 3, q = t & 7;
        const float* src = x + ((size_t)(nbase + g)) * Hd + q * 16;
        float4 a0 = ((const float4*)src)[0], a1 = ((const float4*)src)[1];
        float4 a2 = ((const float4*)src)[2], a3 = ((const float4*)src)[3];
        ((bf16x8*)X)[g * 16 + ((q * 2) ^ (g & 7))]     = cvt8(a0, a1);
        ((bf16x8*)X)[g * 16 + ((q * 2 + 1) ^ (g & 7))] = cvt8(a2, a3);
    }

    bf16x8 wf[4][4];
    #pragma unroll
    for (int nt = 0; nt < 4; nt++) {
        int n = wv * 64 + nt * 16 + row16;
        #pragma unroll
        for (int kt = 0; kt < 4; kt++)
            wf[kt][nt] = *(const bf16x8*)(WabT + n * 128 + kt * 32 + kg * 8);
    }
    __syncthreads();

    f32x4 acc[2][4];
    #pragma unroll
    for (int mt = 0; mt < 2; mt++)
        #pragma unroll
        for (int nt = 0; nt < 4; nt++) acc[mt][nt] = (f32x4){0.f,0.f,0.f,0.f};

    #pragma unroll
    for (int mt = 0; mt < 2; mt++) {
        int row = mt * 16 + row16;
        #pragma unroll
        for (int kt = 0; kt < 4; kt++) {
            bf16x8 xf = ((const bf16x8*)X)[row * 16 + ((kt * 4 + kg) ^ (row & 7))];
            #pragma unroll
            for (int nt = 0; nt < 4; nt++)
                acc[mt][nt] = __builtin_amdgcn_mfma_f32_16x16x32_bf16(wf[kt][nt], xf, acc[mt][nt], 0, 0, 0);
        }
    }

    #pragma unroll
    for (int mt = 0; mt < 2; mt++) {
        size_t node = nbase + mt * 16 + row16;
        #pragma unroll
        for (int nt = 0; nt < 4; nt++) {
            int ch = wv * 64 + nt * 16 + kg * 4;
            uint2 pk = { pk2(acc[mt][nt][0], acc[mt][nt][1]), pk2(acc[mt][nt][2], acc[mt][nt][3]) };
            short* dst = (ch < 128) ? (xa + node * Hd + ch) : (xb + node * Hd + (ch - 128));
            *(uint2*)dst = pk;
        }
    }
}

// ---- edge_mlp: e = relu(ea@W1c + xa[src] + xb[dest] + be1) @ W2 + be2 ----
// 2-deep cross-tile pipeline, ONE non-draining barrier per tile:
//  A: issue ea/ei loads for t+1; L1 GEMM(t); issue xa/xb gathers for t+1
//  B: epilogue(t) -> A2[cur]; stage-write Aea[cur^1] from regs (auto-counted vmcnt)
//  lds_barrier (lgkmcnt only, vmcnt stays in flight)
//  C: L2 GEMM(t) from A2[cur]; direct e stores
__global__ __launch_bounds__(512) void edge_mlp(
    const float* __restrict__ ea, const int* __restrict__ ei,
    const short* __restrict__ xa, const short* __restrict__ xb,
    const short* __restrict__ W1cT, const float* __restrict__ be1,
    const short* __restrict__ W2T, const float* __restrict__ be2,
    float* __restrict__ e_out)
{
    __shared__ __align__(16) short Aea[2][64 * 128];   // 2x16KB input tile (bf16, swizzled)
    __shared__ __align__(16) short A2[2][64 * 128];    // 2x16KB hidden tile

    const int t = threadIdx.x;
    const int wv = t >> 6, lane = t & 63;
    const int row16 = lane & 15, kg = lane >> 4;
    const int n0 = wv * 16 + kg * 4;        // this lane's 4 output channels
    const int srow = t >> 3, sq = t & 7;    // staging: row, 64B quarter

    // per-wave weights (16 cols), resident (32 VGPR) — r5-proven
    bf16x8 w1[4], w2[4];
    {
        const short* wp1 = W1cT + (wv * 16 + row16) * 128 + kg * 8;
        const short* wp2 = W2T  + (wv * 16 + row16) * 128 + kg * 8;
        #pragma unroll
        for (int kt = 0; kt < 4; kt++) {
            w1[kt] = *(const bf16x8*)(wp1 + kt * 32);
            w2[kt] = *(const bf16x8*)(wp2 + kt * 32);
        }
    }
    const float4 b1v = *(const float4*)(be1 + n0);
    const float4 b2v = *(const float4*)(be2 + n0);

    int tile = blockIdx.x * CHUNK;          // first tile always < NT (grid = ceil(NT/CHUNK))

    // ---- prologue: stage tile0 + its gathers ----
    bf16x4 av[4], bv[4];
    {
        int b0 = tile / TPB;
        size_t ebase = (size_t)(tile % TPB) * 64;
        const float* src = ea + ((size_t)b0 * Ee + ebase + srow) * Hd + sq * 16;
        float4 e0 = ((const float4*)src)[0], e1 = ((const float4*)src)[1];
        float4 e2 = ((const float4*)src)[2], e3 = ((const float4*)src)[3];
        int sn[4], dn[4];
        #pragma unroll
        for (int mt = 0; mt < 4; mt++) {
            int eidx = (int)ebase + mt * 16 + row16;
            sn[mt] = ei[eidx]; dn[mt] = ei[Ee + eidx];
        }
        const short* xab = xa + (size_t)b0 * Nn * Hd;
        const short* xbb = xb + (size_t)b0 * Nn * Hd;
        #pragma unroll
        for (int mt = 0; mt < 4; mt++) {
            av[mt] = *(const bf16x4*)(xab + (size_t)sn[mt] * Hd + n0);
            bv[mt] = *(const bf16x4*)(xbb + (size_t)dn[mt] * Hd + n0);
        }
        ((bf16x8*)Aea[0])[srow * 16 + ((sq * 2)     ^ (srow & 7))] = cvt8(e0, e1);
        ((bf16x8*)Aea[0])[srow * 16 + ((sq * 2 + 1) ^ (srow & 7))] = cvt8(e2, e3);
    }
    __syncthreads();

    int cur = 0;
    for (int it = 0; it < CHUNK; ++it) {
        const bool v = (tile < NT);
        const int b = tile / TPB;
        const size_t ebase = (size_t)(tile % TPB) * 64;
        const int ntile = tile + 1;
        const bool nv = (it + 1 < CHUNK) && (ntile < NT);
        const int nb = ntile / TPB;
        const size_t nebase = (size_t)(ntile % TPB) * 64;

        // A1: issue next-tile ea + ei loads (in flight under L1)
        float4 ner0, ner1, ner2, ner3;
        int nsn[4], ndn[4];
        if (nv) {
            const float* src = ea + ((size_t)nb * Ee + nebase + srow) * Hd + sq * 16;
            ner0 = ((const float4*)src)[0]; ner1 = ((const float4*)src)[1];
            ner2 = ((const float4*)src)[2]; ner3 = ((const float4*)src)[3];
            #pragma unroll
            for (int mt = 0; mt < 4; mt++) {
                int neidx = (int)nebase + mt * 16 + row16;
                nsn[mt] = ei[neidx]; ndn[mt] = ei[Ee + neidx];
            }
        }

        // A2: L1 GEMM from Aea[cur]
        f32x4 acc[4];
        #pragma unroll
        for (int mt = 0; mt < 4; mt++) acc[mt] = (f32x4){0.f,0.f,0.f,0.f};
        if (v) {
            #pragma unroll
            for (int kt = 0; kt < 4; kt++) {
                #pragma unroll
                for (int mt = 0; mt < 4; mt++) {
                    int row = mt * 16 + row16;
                    bf16x8 af = ((const bf16x8*)Aea[cur])[row * 16 + ((kt * 4 + kg) ^ (row & 7))];
                    acc[mt] = __builtin_amdgcn_mfma_f32_16x16x32_bf16(w1[kt], af, acc[mt], 0, 0, 0);
                }
            }
        }

        // A3: issue next-tile xa/xb gathers (used in epilogue of t+1)
        bf16x4 nav[4], nbv[4];
        if (nv) {
            const short* xab = xa + (size_t)nb * Nn * Hd;
            const short* xbb = xb + (size_t)nb * Nn * Hd;
            #pragma unroll
            for (int mt = 0; mt < 4; mt++) {
                nav[mt] = *(const bf16x4*)(xab + (size_t)nsn[mt] * Hd + n0);
                nbv[mt] = *(const bf16x4*)(xbb + (size_t)ndn[mt] * Hd + n0);
            }
        }

        // B: epilogue(t) -> A2[cur]; stage Aea[cur^1] for t+1
        if (v) {
            #pragma unroll
            for (int mt = 0; mt < 4; mt++) {
                int row = mt * 16 + row16;
                float vv[4];
                #pragma unroll
                for (int r = 0; r < 4; r++) {
                    float u = acc[mt][r] + b1v[r] + bf2f(av[mt][r]) + bf2f(bv[mt][r]);
                    vv[r] = u > 0.f ? u : 0.f;
                }
                int G = (n0 >> 3) ^ (row & 7);
                *(uint2*)((char*)A2[cur] + row * 256 + G * 16 + (n0 & 7) * 2) =
                    (uint2){ pk2(vv[0], vv[1]), pk2(vv[2], vv[3]) };
            }
        }
        if (nv) {
            ((bf16x8*)Aea[cur ^ 1])[srow * 16 + ((sq * 2)     ^ (srow & 7))] = cvt8(ner0, ner1);
            ((bf16x8*)Aea[cur ^ 1])[srow * 16 + ((sq * 2 + 1) ^ (srow & 7))] = cvt8(ner2, ner3);
        }
        lds_barrier();

        // C: L2 GEMM from A2[cur], direct e stores (fire-and-forget)
        if (v) {
            f32x4 acc2[4];
            #pragma unroll
            for (int mt = 0; mt < 4; mt++) acc2[mt] = (f32x4){0.f,0.f,0.f,0.f};
            #pragma unroll
            for (int kt = 0; kt < 4; kt++) {
                #pragma unroll
                for (int mt = 0; mt < 4; mt++) {
                    int row = mt * 16 + row16;
                    bf16x8 hf = *(const bf16x8*)((const char*)A2[cur] + row * 256 + (((kt * 4 + kg) ^ (row & 7)) * 16));
                    acc2[mt] = __builtin_amdgcn_mfma_f32_16x16x32_bf16(w2[kt], hf, acc2[mt], 0, 0, 0);
                }
            }
            float* eo = e_out + ((size_t)b * Ee + ebase) * Hd;
            #pragma unroll
            for (int mt = 0; mt < 4; mt++) {
                float4 ov;
                ov.x = acc2[mt][0] + b2v.x;
                ov.y = acc2[mt][1] + b2v.y;
                ov.z = acc2[mt][2] + b2v.z;
                ov.w = acc2[mt][3] + b2v.w;
                *(float4*)(eo + (size_t)(mt * 16 + row16) * Hd + n0) = ov;
            }
        }

        // rotate
        #pragma unroll
        for (int mt = 0; mt < 4; mt++) { av[mt] = nav[mt]; bv[mt] = nbv[mt]; }
        cur ^= 1; tile = ntile;
    }
}

// ---- node_mlp: CSR-gather agg from e, x_out = relu(concat(x,agg)@Wn1+bn1)@Wn2+bn2 ----
__global__ __launch_bounds__(512, 4) void node_mlp(
    const float* __restrict__ x, const float* __restrict__ e_out,
    const int* __restrict__ rp, const int* __restrict__ elist,
    const short* __restrict__ Wn1T, const float* __restrict__ bn1,
    const short* __restrict__ Wn2T, const float* __restrict__ bn2,
    float* __restrict__ xout)
{
    __shared__ __align__(16) short A[32 * 256];      // 16KB: [node][32 groups] (x | agg)
    __shared__ __align__(16) short A2[32 * 128];     // 8KB hidden

    const int tilesPerB = (Nn + 31) / 32;            // 1563
    const int bid = blockIdx.x;
    const int b = bid / tilesPerB;
    const int nbase = (bid % tilesPerB) * 32;
    const int t = threadIdx.x;
    const int wv = t >> 6, lane = t & 63;
    const int row16 = lane & 15, kg = lane >> 4;
    const int n0 = wv * 16 + kg * 4;

    // gather + stage: 16 threads per node, 8 floats (32B) each
    {
        int g = t >> 4, q2 = t & 15;
        int n = nbase + g;
        float4 xv0 = {0,0,0,0}, xv1 = xv0;
        float4 s0 = {0,0,0,0}, s1 = s0;
        if (n < Nn) {
            const float* xr = x + ((size_t)b * Nn + n) * Hd + q2 * 8;
            xv0 = ((const float4*)xr)[0]; xv1 = ((const float4*)xr)[1];
            int jb = rp[n], je = rp[n + 1];
            const float* eb = e_out + (size_t)b * Ee * Hd + q2 * 8;
            int j = jb;
            for (; j + 4 <= je; j += 4) {
                int e0 = elist[j], e1 = elist[j+1], e2 = elist[j+2], e3 = elist[j+3];
                const float* p0 = eb + (size_t)e0 * Hd;
                const float* p1 = eb + (size_t)e1 * Hd;
                const float* p2 = eb + (size_t)e2 * Hd;
                const float* p3 = eb + (size_t)e3 * Hd;
                float4 u0 = ((const float4*)p0)[0], u1 = ((const float4*)p0)[1];
                float4 u2 = ((const float4*)p1)[0], u3 = ((const float4*)p1)[1];
                float4 u4 = ((const float4*)p2)[0], u5 = ((const float4*)p2)[1];
                float4 u6 = ((const float4*)p3)[0], u7 = ((const float4*)p3)[1];
                s0.x += (u0.x + u2.x) + (u4.x + u6.x);
                s0.y += (u0.y + u2.y) + (u4.y + u6.y);
                s0.z += (u0.z + u2.z) + (u4.z + u6.z);
                s0.w += (u0.w + u2.w) + (u4.w + u6.w);
                s1.x += (u1.x + u3.x) + (u5.x + u7.x);
                s1.y += (u1.y + u3.y) + (u5.y + u7.y);
                s1.z += (u1.z + u3.z) + (u5.z + u7.z);
                s1.w += (u1.w + u3.w) + (u5.w + u7.w);
            }
            for (; j < je; j++) {
                const float* p0 = eb + (size_t)elist[j] * Hd;
                float4 u0 = ((const float4*)p0)[0], u1 = ((const float4*)p0)[1];
                s0.x += u0.x; s0.y += u0.y; s0.z += u0.z; s0.w += u0.w;
                s1.x += u1.x; s1.y += u1.y; s1.z += u1.z; s1.w += u1.w;
            }
        }
        ((bf16x8*)A)[g * 32 + (q2 ^ (g & 7))]        = cvt8(xv0, xv1);
        ((bf16x8*)A)[g * 32 + ((16 + q2) ^ (g & 7))] = cvt8(s0, s1);
    }

    bf16x8 w1[8];
    {
        const short* wp = Wn1T + (wv * 16 + row16) * 256 + kg * 8;
        #pragma unroll
        for (int kt = 0; kt < 8; kt++) w1[kt] = *(const bf16x8*)(wp + kt * 32);
    }
    __syncthreads();

    // L1 GEMM K=256
    f32x4 acc[2];
    acc[0] = (f32x4){0.f,0.f,0.f,0.f}; acc[1] = (f32x4){0.f,0.f,0.f,0.f};
    #pragma unroll
    for (int kt = 0; kt < 8; kt++) {
        #pragma unroll
        for (int mt = 0; mt < 2; mt++) {
            int row = mt * 16 + row16;
            bf16x8 af = ((const bf16x8*)A)[row * 32 + ((kt * 4 + kg) ^ (row & 7))];
            acc[mt] = __builtin_amdgcn_mfma_f32_16x16x32_bf16(w1[kt], af, acc[mt], 0, 0, 0);
        }
    }

    float4 b1v = *(const float4*)(bn1 + n0);
    bf16x8 w2[4];
    {
        const short* wp = Wn2T + (wv * 16 + row16) * 128 + kg * 8;
        #pragma unroll
        for (int kt = 0; kt < 4; kt++) w2[kt] = *(const bf16x8*)(wp + kt * 32);
    }

    #pragma unroll
    for (int mt = 0; mt < 2; mt++) {
        int row = mt * 16 + row16;
        float v[4];
        #pragma unroll
        for (int r = 0; r < 4; r++) {
            float u = acc[mt][r] + b1v[r];
            v[r] = u > 0.f ? u : 0.f;
        }
        int G = (n0 >> 3) ^ (row & 7);
        *(uint2*)((char*)A2 + row * 256 + G * 16 + (n0 & 7) * 2) = (uint2){ pk2(v[0], v[1]), pk2(v[2], v[3]) };
    }
    __syncthreads();

    // L2 GEMM K=128, direct stores
    f32x4 acc2[2];
    acc2[0] = (f32x4){0.f,0.f,0.f,0.f}; acc2[1] = (f32x4){0.f,0.f,0.f,0.f};
    #pragma unroll
    for (int kt = 0; kt < 4; kt++) {
        #pragma unroll
        for (int mt = 0; mt < 2; mt++) {
            int row = mt * 16 + row16;
            bf16x8 hf = *(const bf16x8*)((const char*)A2 + row * 256 + (((kt * 4 + kg) ^ (row & 7)) * 16));
            acc2[mt] = __builtin_amdgcn_mfma_f32_16x16x32_bf16(w2[kt], hf, acc2[mt], 0, 0, 0);
        }
    }
    float4 b2v = *(const float4*)(bn2 + n0);
    #pragma unroll
    for (int mt = 0; mt < 2; mt++) {
        int node = nbase + mt * 16 + row16;
        if (node < Nn) {
            float4 ov;
            ov.x = acc2[mt][0] + b2v.x;
            ov.y = acc2[mt][1] + b2v.y;
            ov.z = acc2[mt][2] + b2v.z;
            ov.w = acc2[mt][3] + b2v.w;
            *(float4*)(xout + ((size_t)b * Nn + node) * Hd + n0) = ov;
        }
    }
}

extern "C" void kernel_launch(void* const* d_in, const int* in_sizes, int n_in,
                              void* d_out, int out_size, void* d_ws, size_t ws_size,
                              hipStream_t stream) {
    const float* x   = (const float*)d_in[0];
    const int*   ei  = (const int*)d_in[1];
    const float* ea  = (const float*)d_in[2];
    const float* We1 = (const float*)d_in[3];
    const float* be1 = (const float*)d_in[4];
    const float* We2 = (const float*)d_in[5];
    const float* be2 = (const float*)d_in[6];
    const float* Wn1 = (const float*)d_in[7];
    const float* bn1 = (const float*)d_in[8];
    const float* Wn2 = (const float*)d_in[9];
    const float* bn2 = (const float*)d_in[10];

    float* xout  = (float*)d_out;
    float* e_out = xout + (size_t)Bb * Nn * Hd;     // outputs: x_out, then e

    short* wbuf  = (short*)d_ws;                    // 114688 shorts
    short* xa    = wbuf + 114688;                   // NROWS*128 bf16
    short* xb    = xa + (size_t)NROWS * Hd;
    int*   cnt   = (int*)(xb + (size_t)NROWS * Hd);
    int*   cur   = cnt + Nn;
    int*   rp    = cur + Nn;                        // Nn+1
    int*   part  = rp + Nn + 1;                     // 256
    int*   elist = part + 256;                      // Ee

    hipMemsetAsync(cnt, 0, Nn * sizeof(int), stream);
    prep_weights<<<448, 256, 0, stream>>>(We1, We2, Wn1, Wn2, wbuf);
    hist_kernel<<<(Ee + 255) / 256, 256, 0, stream>>>(ei, cnt);
    scan1<<<196, 256, 0, stream>>>(cnt, cur, part);
    scan2<<<1, 64, 0, stream>>>(part);
    scan3<<<196, 256, 0, stream>>>(cur, part, rp);
    scatter_k<<<(Ee + 255) / 256, 256, 0, stream>>>(ei, cur, elist);

    node_pre<<<NROWS / 32, 256, 0, stream>>>(x, wbuf, xa, xb);

    edge_mlp<<<(NT + CHUNK - 1) / CHUNK, 512, 0, stream>>>(
        ea, ei, xa, xb, wbuf + 32768, be1, wbuf + 49152, be2, e_out);

    node_mlp<<<Bb * ((Nn + 31) / 32), 512, 0, stream>>>(
        x, e_out, rp, elist, wbuf + 65536, bn1, wbuf + 98304, bn2, xout);
}